// Round 1
// baseline (1362.039 us; speedup 1.0000x reference)
//
#include <hip/hip_runtime.h>

#define BB 2
#define SS 2048
#define DM 1024
#define NH 16
#define DH 64
#define BP (BB*SS)   // 4096

// ---------------------------------------------------------------------------
// Kernel 1: QKV projection.  out[bp, h, k] = x[bp,:] @ W[h,:,k] + bias[h,k]
// grid = (BP/64, 3*NH); block = 256. Each block: 64x64 output tile, BK=16.
// Outputs stored [B][H][S][DH] for attention-friendly access.
// ---------------------------------------------------------------------------
__global__ __launch_bounds__(256) void k_qkv(
    const float* __restrict__ x,
    const float* __restrict__ Qs, const float* __restrict__ Qbs,
    const float* __restrict__ Ks, const float* __restrict__ Kbs,
    const float* __restrict__ Vs, const float* __restrict__ Vbs,
    float* __restrict__ qb, float* __restrict__ kb, float* __restrict__ vb)
{
    __shared__ float As[16][65];   // [k][m]
    __shared__ float Bs[16][65];   // [k][n]

    const int tid = threadIdx.x;
    const int tx = tid & 15, ty = tid >> 4;
    const int rt = blockIdx.x;
    const int ct = blockIdx.y;          // 0..47 : set*16 + h
    const int set = ct >> 4, h = ct & 15;

    const float* W  = (set == 0) ? Qs  : (set == 1) ? Ks  : Vs;
    const float* Bi = (set == 0) ? Qbs : (set == 1) ? Kbs : Vbs;
    float* out      = (set == 0) ? qb  : (set == 1) ? kb  : vb;
    const float* Wh = W + (size_t)h * DM * DH;   // [DM][64]
    const int row0 = rt * 64;

    float acc[4][4] = {};

    for (int kk = 0; kk < DM; kk += 16) {
        // stage x tile: 64 rows x 16 k
        #pragma unroll
        for (int i = 0; i < 4; ++i) {
            int m = (tid >> 4) + i * 16;
            As[tid & 15][m] = x[(size_t)(row0 + m) * DM + kk + (tid & 15)];
        }
        // stage W tile: 16 k-rows x 64 cols (contiguous float4)
        {
            int k = tid >> 4;
            int n = (tid & 15) * 4;
            float4 w4 = *(const float4*)(Wh + (size_t)(kk + k) * DH + n);
            Bs[k][n] = w4.x; Bs[k][n + 1] = w4.y; Bs[k][n + 2] = w4.z; Bs[k][n + 3] = w4.w;
        }
        __syncthreads();
        #pragma unroll
        for (int k = 0; k < 16; ++k) {
            float a[4], b[4];
            #pragma unroll
            for (int i = 0; i < 4; ++i) a[i] = As[k][ty * 4 + i];
            #pragma unroll
            for (int j = 0; j < 4; ++j) b[j] = Bs[k][tx * 4 + j];
            #pragma unroll
            for (int i = 0; i < 4; ++i)
                #pragma unroll
                for (int j = 0; j < 4; ++j) acc[i][j] += a[i] * b[j];
        }
        __syncthreads();
    }

    // epilogue: bias + store to [B][H][S][DH]
    #pragma unroll
    for (int i = 0; i < 4; ++i) {
        int r  = row0 + ty * 4 + i;       // global bp row
        int b_ = r >> 11;                 // / 2048
        int p  = r & 2047;
        float* dst = out + (((size_t)(b_ * NH + h) * SS + p) << 6);
        #pragma unroll
        for (int j = 0; j < 4; ++j) {
            int n = tx * 4 + j;
            dst[n] = acc[i][j] + Bi[h * DH + n];
        }
    }
}

// ---------------------------------------------------------------------------
// Kernel 2: causal flash attention per (b,h,q-tile of 64 rows).
// q/k/v layout [B][H][S][DH]. Writes z as [bp][H*DH] row-major.
// 256 threads; thread (tx,ty) owns rows ty*4..+3, cols tx*4..+3.
// Q/K tiles XOR-swizzled in LDS so float4 reads are ~conflict-free.
// ---------------------------------------------------------------------------
__global__ __launch_bounds__(256) void k_attn(
    const float* __restrict__ qg, const float* __restrict__ kg,
    const float* __restrict__ vg, float* __restrict__ zg)
{
    __shared__ __align__(16) float Qt[64 * 64];
    __shared__ __align__(16) float Kt[64 * 64];
    __shared__ __align__(16) float Vt[64 * 64];
    __shared__ float P[64][65];

    const int tid = threadIdx.x;
    const int tx = tid & 15, ty = tid >> 4;
    const int qt = (int)gridDim.x - 1 - (int)blockIdx.x;  // long blocks first
    const int bh = blockIdx.y;                            // b*NH + h
    const size_t base = (size_t)bh * SS * DH;

    // stage Q tile (swizzled row-major)
    {
        const float* src = qg + base + (size_t)qt * 64 * DH;
        #pragma unroll
        for (int i = 0; i < 4; ++i) {
            int r  = (tid >> 4) + i * 16;
            int d4 = (tid & 15) * 4;
            float4 w = *(const float4*)(src + r * DH + d4);
            *(float4*)(&Qt[r * 64 + (d4 ^ ((r & 15) << 2))]) = w;
        }
    }

    float zacc[4][4] = {};
    float mrow[4], lrow[4];
    #pragma unroll
    for (int i = 0; i < 4; ++i) { mrow[i] = -1e30f; lrow[i] = 0.f; }

    for (int jt = 0; jt <= qt; ++jt) {
        __syncthreads();   // previous PV done (Vt, P free); Qt staged
        const float* ks = kg + base + (size_t)jt * 64 * DH;
        const float* vs = vg + base + (size_t)jt * 64 * DH;
        #pragma unroll
        for (int i = 0; i < 4; ++i) {
            int c  = (tid >> 4) + i * 16;
            int d4 = (tid & 15) * 4;
            float4 w = *(const float4*)(ks + c * DH + d4);
            *(float4*)(&Kt[c * 64 + (d4 ^ ((c & 15) << 2))]) = w;
            float4 u = *(const float4*)(vs + c * DH + d4);
            *(float4*)(&Vt[c * 64 + d4]) = u;
        }
        __syncthreads();

        // s = (Q K^T) / 8
        float s[4][4] = {};
        #pragma unroll 4
        for (int d0 = 0; d0 < 64; d0 += 4) {
            float4 qv[4], kv[4];
            #pragma unroll
            for (int i = 0; i < 4; ++i) {
                int r = ty * 4 + i;
                qv[i] = *(const float4*)(&Qt[r * 64 + (d0 ^ ((r & 15) << 2))]);
            }
            #pragma unroll
            for (int j = 0; j < 4; ++j) {
                int c = tx * 4 + j;
                kv[j] = *(const float4*)(&Kt[c * 64 + (d0 ^ ((c & 15) << 2))]);
            }
            #pragma unroll
            for (int i = 0; i < 4; ++i)
                #pragma unroll
                for (int j = 0; j < 4; ++j)
                    s[i][j] += qv[i].x * kv[j].x + qv[i].y * kv[j].y
                             + qv[i].z * kv[j].z + qv[i].w * kv[j].w;
        }

        // scale + causal mask (only the diagonal tile is partial)
        #pragma unroll
        for (int i = 0; i < 4; ++i)
            #pragma unroll
            for (int j = 0; j < 4; ++j) {
                s[i][j] *= 0.125f;
                if (jt == qt && (tx * 4 + j) > (ty * 4 + i)) s[i][j] = -1e30f;
            }

        // online softmax update
        #pragma unroll
        for (int i = 0; i < 4; ++i) {
            float mx = fmaxf(fmaxf(s[i][0], s[i][1]), fmaxf(s[i][2], s[i][3]));
            #pragma unroll
            for (int o = 1; o < 16; o <<= 1) mx = fmaxf(mx, __shfl_xor(mx, o, 64));
            float mnew = fmaxf(mrow[i], mx);
            float corr = __expf(mrow[i] - mnew);
            mrow[i] = mnew;
            float rs = 0.f;
            #pragma unroll
            for (int j = 0; j < 4; ++j) { s[i][j] = __expf(s[i][j] - mnew); rs += s[i][j]; }
            #pragma unroll
            for (int o = 1; o < 16; o <<= 1) rs += __shfl_xor(rs, o, 64);
            lrow[i] = lrow[i] * corr + rs;
            #pragma unroll
            for (int j = 0; j < 4; ++j) zacc[i][j] *= corr;
            #pragma unroll
            for (int j = 0; j < 4; ++j) P[ty * 4 + i][tx * 4 + j] = s[i][j];
        }
        __syncthreads();

        // z += P @ V
        #pragma unroll 4
        for (int c = 0; c < 64; ++c) {
            float4 vv = *(const float4*)(&Vt[c * 64 + tx * 4]);
            #pragma unroll
            for (int i = 0; i < 4; ++i) {
                float p = P[ty * 4 + i][c];
                zacc[i][0] += p * vv.x; zacc[i][1] += p * vv.y;
                zacc[i][2] += p * vv.z; zacc[i][3] += p * vv.w;
            }
        }
    }

    // epilogue: normalize, write z[bp][h*64 + d]
    const int b_ = bh >> 4, h = bh & 15;
    #pragma unroll
    for (int i = 0; i < 4; ++i) {
        int p = qt * 64 + ty * 4 + i;
        float inv = 1.f / lrow[i];
        float4 o4;
        o4.x = zacc[i][0] * inv; o4.y = zacc[i][1] * inv;
        o4.z = zacc[i][2] * inv; o4.w = zacc[i][3] * inv;
        *(float4*)(zg + (size_t)(b_ * SS + p) * DM + h * DH + tx * 4) = o4;
    }
}

// ---------------------------------------------------------------------------
// Kernel 3: out = z @ O_flat + Ob.   z:[BP][DM], O_flat:[DM][DM] (row=h*64+k).
// ---------------------------------------------------------------------------
__global__ __launch_bounds__(256) void k_out(
    const float* __restrict__ z, const float* __restrict__ O,
    const float* __restrict__ Ob, float* __restrict__ out)
{
    __shared__ float As[16][65];
    __shared__ float Bs[16][65];

    const int tid = threadIdx.x;
    const int tx = tid & 15, ty = tid >> 4;
    const int row0 = blockIdx.x * 64;
    const int c0   = blockIdx.y * 64;

    float acc[4][4] = {};

    for (int kk = 0; kk < DM; kk += 16) {
        #pragma unroll
        for (int i = 0; i < 4; ++i) {
            int m = (tid >> 4) + i * 16;
            As[tid & 15][m] = z[(size_t)(row0 + m) * DM + kk + (tid & 15)];
        }
        {
            int k = tid >> 4;
            int n = (tid & 15) * 4;
            float4 w4 = *(const float4*)(O + (size_t)(kk + k) * DM + c0 + n);
            Bs[k][n] = w4.x; Bs[k][n + 1] = w4.y; Bs[k][n + 2] = w4.z; Bs[k][n + 3] = w4.w;
        }
        __syncthreads();
        #pragma unroll
        for (int k = 0; k < 16; ++k) {
            float a[4], b[4];
            #pragma unroll
            for (int i = 0; i < 4; ++i) a[i] = As[k][ty * 4 + i];
            #pragma unroll
            for (int j = 0; j < 4; ++j) b[j] = Bs[k][tx * 4 + j];
            #pragma unroll
            for (int i = 0; i < 4; ++i)
                #pragma unroll
                for (int j = 0; j < 4; ++j) acc[i][j] += a[i] * b[j];
        }
        __syncthreads();
    }

    #pragma unroll
    for (int i = 0; i < 4; ++i) {
        int r = row0 + ty * 4 + i;
        #pragma unroll
        for (int j = 0; j < 4; ++j) {
            int n = c0 + tx * 4 + j;
            out[(size_t)r * DM + n] = acc[i][j] + Ob[n];
        }
    }
}

// ---------------------------------------------------------------------------
extern "C" void kernel_launch(void* const* d_in, const int* in_sizes, int n_in,
                              void* d_out, int out_size, void* d_ws, size_t ws_size,
                              hipStream_t stream)
{
    const float* x   = (const float*)d_in[0];
    const float* Qs  = (const float*)d_in[1];
    const float* Qbs = (const float*)d_in[2];
    const float* Ks  = (const float*)d_in[3];
    const float* Kbs = (const float*)d_in[4];
    const float* Vs  = (const float*)d_in[5];
    const float* Vbs = (const float*)d_in[6];
    const float* O   = (const float*)d_in[7];
    const float* Ob  = (const float*)d_in[8];
    float* out = (float*)d_out;

    const size_t NELEM = (size_t)BP * DM;   // 4,194,304 floats per buffer
    float* q = (float*)d_ws;
    float* k = q + NELEM;
    float* v = k + NELEM;
    float* z = v + NELEM;

    k_qkv<<<dim3(BP / 64, 3 * NH), 256, 0, stream>>>(x, Qs, Qbs, Ks, Kbs, Vs, Vbs, q, k, v);
    k_attn<<<dim3(SS / 64, BB * NH), 256, 0, stream>>>(q, k, v, z);
    k_out<<<dim3(BP / 64, DM / 64), 256, 0, stream>>>(z, O, Ob, out);
}

// Round 4
// 381.988 us; speedup vs baseline: 3.5657x; 3.5657x over previous
//
#include <hip/hip_runtime.h>

#define BB 2
#define SS 2048
#define DM 1024
#define NH 16
#define DH 64
#define BP (BB*SS)            // 4096
#define BHSD (BB*NH*SS*DH)    // 4,194,304 elements

typedef __attribute__((ext_vector_type(8))) short short8v;   // 8 x bf16 (4 VGPR)
typedef __attribute__((ext_vector_type(4))) float float4v;   // MFMA C/D

// round-to-nearest-even fp32 -> bf16 (finite inputs)
__device__ __forceinline__ unsigned short f2bf(float f) {
    unsigned int u = __float_as_uint(f);
    u += 0x7fffu + ((u >> 16) & 1u);
    return (unsigned short)(u >> 16);
}

// async global->LDS, 16B per lane; LDS dest = wave-uniform base + lane*16
__device__ __forceinline__ void async_cp16(const void* g, void* l) {
    __builtin_amdgcn_global_load_lds(
        (const __attribute__((address_space(1))) unsigned int*)g,
        (__attribute__((address_space(3))) unsigned int*)l, 16, 0, 0);
}

// ---------------------------------------------------------------------------
// x (fp32 [4096][1024]) -> xb (bf16), vectorized 8/thread
// ---------------------------------------------------------------------------
__global__ __launch_bounds__(256) void k_cvtx(const float* __restrict__ x,
                                              unsigned short* __restrict__ xb) {
    const size_t i = (size_t)blockIdx.x * 256 + threadIdx.x;
    const float4 a = ((const float4*)x)[i * 2];
    const float4 b = ((const float4*)x)[i * 2 + 1];
    uint4 o;
    o.x = f2bf(a.x) | ((unsigned)f2bf(a.y) << 16);
    o.y = f2bf(a.z) | ((unsigned)f2bf(a.w) << 16);
    o.z = f2bf(b.x) | ((unsigned)f2bf(b.y) << 16);
    o.w = f2bf(b.z) | ((unsigned)f2bf(b.w) << 16);
    ((uint4*)xb)[i] = o;
}

// ---------------------------------------------------------------------------
// Weight repack: transpose+convert fp32 [1024][C] -> bf16 [C][1024].
// z<48: QKV head matrices (C=64) -> WbT rows (set*16+h)*64+dh.  z=48: O -> ObT.
// ---------------------------------------------------------------------------
__global__ __launch_bounds__(256) void k_wrepack(
    const float* __restrict__ Qs, const float* __restrict__ Ks,
    const float* __restrict__ Vs, const float* __restrict__ O,
    unsigned short* __restrict__ WbT, unsigned short* __restrict__ ObT)
{
    __shared__ float t[64][65];
    const int z = blockIdx.z;
    const float* src; unsigned short* dst; int C;
    if (z < 48) {
        if (blockIdx.y != 0) return;          // block-uniform early exit
        const int set = z >> 4, h = z & 15;
        src = ((set == 0) ? Qs : (set == 1) ? Ks : Vs) + (size_t)h * DM * DH;
        dst = WbT + (size_t)z * DH * DM;
        C = DH;
    } else { src = O; dst = ObT; C = DM; }
    const int r0 = blockIdx.x * 64, c0 = blockIdx.y * 64;
    const int tid = threadIdx.x, c = tid & 63, r4 = tid >> 6;
    #pragma unroll
    for (int i = 0; i < 16; ++i) {
        int r = r4 + i * 4;
        t[r][c] = src[(size_t)(r0 + r) * C + c0 + c];
    }
    __syncthreads();
    #pragma unroll
    for (int i = 0; i < 16; ++i) {
        int rr = r4 + i * 4;                  // source col within tile
        dst[(size_t)(c0 + rr) * DM + r0 + c] = f2bf(t[c][rr]);  // pad-65: conflict-free
    }
}

// ---------------------------------------------------------------------------
// bf16 transpose v [b][h][s][64] -> vT [b][h][64][s]
// ---------------------------------------------------------------------------
__global__ __launch_bounds__(256) void k_vt(const unsigned short* __restrict__ v,
                                            unsigned short* __restrict__ vT) {
    __shared__ unsigned short t[64][66];      // pad 66: col-read 2-way (free)
    const int bh = blockIdx.y;
    const int s0 = blockIdx.x * 64;
    const unsigned short* src = v + (size_t)bh * SS * DH + (size_t)s0 * DH;
    unsigned short* dst = vT + (size_t)bh * DH * SS + s0;
    const int tid = threadIdx.x, c = tid & 63, r4 = tid >> 6;
    #pragma unroll
    for (int i = 0; i < 16; ++i) { int r = r4 + i * 4; t[r][c] = src[r * DH + c]; }
    __syncthreads();
    #pragma unroll
    for (int i = 0; i < 16; ++i) { int dr = r4 + i * 4; dst[(size_t)dr * SS + c] = t[c][dr]; }
}

// ---------------------------------------------------------------------------
// bf16 MFMA GEMM, m97 structure: C[M][N] = A[M][K] * B[N][K]^T.
// 128x128 tile, BK=32, 4 waves (2x2), each wave 64x64 = 4x4 MFMA frags.
// MODE 0: qkv epilogue (bf16, scatter to [set][b][h][s][dh], +bias per set)
// MODE 1: fp32 row-major out, +bias
// ---------------------------------------------------------------------------
template<int MODE>
__global__ __launch_bounds__(256) void k_gemm(
    const unsigned short* __restrict__ A, const unsigned short* __restrict__ Bm,
    void* __restrict__ Cout, int N, int K,
    const float* __restrict__ bq, const float* __restrict__ bk,
    const float* __restrict__ bv)
{
    __shared__ __align__(16) unsigned short Al[128 * 32];   // [row][32k] linear, 64B rows
    __shared__ __align__(16) unsigned short Bl[128 * 32];
    const int tid = threadIdx.x;
    const int w = tid >> 6, l = tid & 63;
    const int ll = l & 15, lh = l >> 4;
    const int m0 = blockIdx.x * 128, n0 = blockIdx.y * 128;
    const int wm = w >> 1, wn = w & 1;
    const int sr = l >> 2, sc = l & 3;        // staging: lane -> (row, 16B-chunk)

    const float4v vzero = {0.f, 0.f, 0.f, 0.f};
    float4v acc[4][4];
    #pragma unroll
    for (int i = 0; i < 4; ++i)
        #pragma unroll
        for (int j = 0; j < 4; ++j) acc[i][j] = vzero;

    for (int k0 = 0; k0 < K; k0 += 32) {
        __syncthreads();                      // previous tile fully consumed
        #pragma unroll
        for (int half = 0; half < 2; ++half) {
            const int r = w * 32 + half * 16 + sr;
            async_cp16(A + (size_t)(m0 + r) * K + k0 + sc * 8,
                       &Al[(w * 32 + half * 16) * 32]);
            async_cp16(Bm + (size_t)(n0 + r) * K + k0 + sc * 8,
                       &Bl[(w * 32 + half * 16) * 32]);
        }
        __syncthreads();                      // compiler drains vmcnt before barrier

        short8v af[4], bfr[4];
        #pragma unroll
        for (int mi = 0; mi < 4; ++mi)
            af[mi] = *(const short8v*)&Al[(wm * 64 + mi * 16 + ll) * 32 + lh * 8];
        #pragma unroll
        for (int ni = 0; ni < 4; ++ni)
            bfr[ni] = *(const short8v*)&Bl[(wn * 64 + ni * 16 + ll) * 32 + lh * 8];
        #pragma unroll
        for (int mi = 0; mi < 4; ++mi)
            #pragma unroll
            for (int ni = 0; ni < 4; ++ni)
                acc[mi][ni] = __builtin_amdgcn_mfma_f32_16x16x32_bf16(
                    af[mi], bfr[ni], acc[mi][ni], 0, 0, 0);
    }

    // epilogue: C/D layout col=lane&15, row=(lane>>4)*4+reg  [m89-verified]
    #pragma unroll
    for (int mi = 0; mi < 4; ++mi)
        #pragma unroll
        for (int ni = 0; ni < 4; ++ni)
            #pragma unroll
            for (int r = 0; r < 4; ++r) {
                const int gm = m0 + wm * 64 + mi * 16 + lh * 4 + r;
                const int gn = n0 + wn * 64 + ni * 16 + ll;
                float val = acc[mi][ni][r];
                if (MODE == 0) {
                    const int set = gn >> 10, h = (gn >> 6) & 15, dh = gn & 63;
                    const float* bias = (set == 0) ? bq : (set == 1) ? bk : bv;
                    val += bias[(h << 6) + dh];
                    const int b_ = gm >> 11, s = gm & 2047;
                    ((unsigned short*)Cout)[(size_t)set * BHSD +
                        (((size_t)(b_ * NH + h) * SS + s) << 6) + dh] = f2bf(val);
                } else {
                    val += bq[gn];
                    ((float*)Cout)[(size_t)gm * N + gn] = val;
                }
            }
}

// ---------------------------------------------------------------------------
// Flash attention, bf16 MFMA. Grid (32 qt, 32 bh), 4 waves/block, zero barriers.
// Wave w owns q rows qt*64 + w*16 .. +16. K/V frags read direct from global
// (L2-resident). P re-layout via wave-private LDS [16][68] f32.
// ---------------------------------------------------------------------------
__global__ __launch_bounds__(256) void k_attn(
    const unsigned short* __restrict__ qg, const unsigned short* __restrict__ kg,
    const unsigned short* __restrict__ vtg, unsigned short* __restrict__ zg)
{
    __shared__ __align__(16) float Plds[4][16][68];
    const int tid = threadIdx.x, w = tid >> 6, l = tid & 63;
    const int ll = l & 15, lh = l >> 4;
    const int qt = (int)gridDim.x - 1 - (int)blockIdx.x;   // heavy tiles first
    const int bh = blockIdx.y;
    const int q0 = qt * 64 + w * 16;
    const unsigned short* qb = qg + (size_t)bh * SS * DH;
    const unsigned short* kb = kg + (size_t)bh * SS * DH;
    const unsigned short* vb = vtg + (size_t)bh * DH * SS;

    short8v qf[2];      // A-frag: lane holds Q[row=ll][k=lh*8+j] (+32 for second)
    qf[0] = *(const short8v*)(qb + (size_t)(q0 + ll) * DH + lh * 8);
    qf[1] = *(const short8v*)(qb + (size_t)(q0 + ll) * DH + 32 + lh * 8);

    const float4v vzero = {0.f, 0.f, 0.f, 0.f};
    float4v zacc[4];
    #pragma unroll
    for (int n = 0; n < 4; ++n) zacc[n] = vzero;
    float mrow[4] = {-1e30f, -1e30f, -1e30f, -1e30f};
    float lrow[4] = {0.f, 0.f, 0.f, 0.f};

    for (int jt = 0; jt <= qt; ++jt) {
        // ---- S = Q K^T / 8 ----
        const unsigned short* kt = kb + (size_t)jt * 64 * DH;
        float4v sv[4];
        #pragma unroll
        for (int n = 0; n < 4; ++n) {
            short8v kf0 = *(const short8v*)(kt + (size_t)(n * 16 + ll) * DH + lh * 8);
            short8v kf1 = *(const short8v*)(kt + (size_t)(n * 16 + ll) * DH + 32 + lh * 8);
            float4v t = vzero;
            t = __builtin_amdgcn_mfma_f32_16x16x32_bf16(qf[0], kf0, t, 0, 0, 0);
            t = __builtin_amdgcn_mfma_f32_16x16x32_bf16(qf[1], kf1, t, 0, 0, 0);
            sv[n] = t;
        }
        const bool diag = (jt == qt);
        #pragma unroll
        for (int n = 0; n < 4; ++n)
            #pragma unroll
            for (int r = 0; r < 4; ++r) {
                float xv = sv[n][r] * 0.125f;
                if (diag && (jt * 64 + n * 16 + ll) > (q0 + lh * 4 + r)) xv = -1e30f;
                sv[n][r] = xv;
            }
        // ---- online softmax (rows = lh*4+r; 16 lanes of same lh share a row) ----
        #pragma unroll
        for (int r = 0; r < 4; ++r) {
            float mx = fmaxf(fmaxf(sv[0][r], sv[1][r]), fmaxf(sv[2][r], sv[3][r]));
            #pragma unroll
            for (int o = 1; o < 16; o <<= 1) mx = fmaxf(mx, __shfl_xor(mx, o, 64));
            const float mn = fmaxf(mrow[r], mx);
            const float corr = __expf(mrow[r] - mn);
            mrow[r] = mn;
            float rs = 0.f;
            #pragma unroll
            for (int n = 0; n < 4; ++n) {
                const float p = __expf(sv[n][r] - mn);
                sv[n][r] = p; rs += p;
            }
            #pragma unroll
            for (int o = 1; o < 16; o <<= 1) rs += __shfl_xor(rs, o, 64);
            lrow[r] = lrow[r] * corr + rs;
            #pragma unroll
            for (int n = 0; n < 4; ++n) zacc[n][r] *= corr;
            #pragma unroll
            for (int n = 0; n < 4; ++n) Plds[w][lh * 4 + r][n * 16 + ll] = sv[n][r];
        }
        // ---- P (C-layout) -> A-frags via wave-private LDS; cvt to bf16 ----
        short8v pa[2];
        #pragma unroll
        for (int kk = 0; kk < 2; ++kk)
            #pragma unroll
            for (int j = 0; j < 8; ++j)
                pa[kk][j] = (short)f2bf(Plds[w][ll][kk * 32 + lh * 8 + j]);
        // ---- z += P @ V  (B-frag from transposed V: 16B contiguous) ----
        const unsigned short* vt = vb + jt * 64;
        #pragma unroll
        for (int n = 0; n < 4; ++n) {
            short8v vf0 = *(const short8v*)(vt + (size_t)(n * 16 + ll) * SS + lh * 8);
            short8v vf1 = *(const short8v*)(vt + (size_t)(n * 16 + ll) * SS + 32 + lh * 8);
            zacc[n] = __builtin_amdgcn_mfma_f32_16x16x32_bf16(pa[0], vf0, zacc[n], 0, 0, 0);
            zacc[n] = __builtin_amdgcn_mfma_f32_16x16x32_bf16(pa[1], vf1, zacc[n], 0, 0, 0);
        }
    }

    // epilogue: z[bp][h*64+dh] bf16
    const int b_ = bh >> 4, h = bh & 15;
    float inv[4];
    #pragma unroll
    for (int r = 0; r < 4; ++r) inv[r] = 1.f / lrow[r];
    #pragma unroll
    for (int n = 0; n < 4; ++n)
        #pragma unroll
        for (int r = 0; r < 4; ++r) {
            const int s = qt * 64 + w * 16 + lh * 4 + r;
            zg[(((size_t)(b_ * SS + s)) << 10) + (h << 6) + n * 16 + ll] =
                f2bf(zacc[n][r] * inv[r]);
        }
}

// ---------------------------------------------------------------------------
extern "C" void kernel_launch(void* const* d_in, const int* in_sizes, int n_in,
                              void* d_out, int out_size, void* d_ws, size_t ws_size,
                              hipStream_t stream)
{
    const float* x   = (const float*)d_in[0];
    const float* Qs  = (const float*)d_in[1];
    const float* Qbs = (const float*)d_in[2];
    const float* Ks  = (const float*)d_in[3];
    const float* Kbs = (const float*)d_in[4];
    const float* Vs  = (const float*)d_in[5];
    const float* Vbs = (const float*)d_in[6];
    const float* O   = (const float*)d_in[7];
    const float* Ob  = (const float*)d_in[8];

    unsigned short* xb  = (unsigned short*)d_ws;          // [4096][1024]
    unsigned short* WbT = xb  + (size_t)BP * DM;          // [3072][1024]
    unsigned short* ObT = WbT + (size_t)3 * NH * DH * DM; // [1024][1024]
    unsigned short* qkv = ObT + (size_t)DM * DM;          // 3 x [b][h][s][dh]
    unsigned short* vT  = qkv + (size_t)3 * BHSD;         // [b][h][dh][s]
    unsigned short* z   = vT  + (size_t)BHSD;             // [4096][1024]

    k_cvtx<<<dim3(BP * DM / 2048), 256, 0, stream>>>(x, xb);
    k_wrepack<<<dim3(16, 16, 49), 256, 0, stream>>>(Qs, Ks, Vs, O, WbT, ObT);
    k_gemm<0><<<dim3(BP / 128, 3 * DM / 128), 256, 0, stream>>>(
        xb, WbT, qkv, 3 * DM, DM, Qbs, Kbs, Vbs);
    k_vt<<<dim3(SS / 64, BB * NH), 256, 0, stream>>>(qkv + (size_t)2 * BHSD, vT);
    k_attn<<<dim3(SS / 64, BB * NH), 256, 0, stream>>>(qkv, qkv + BHSD, vT, z);
    k_gemm<1><<<dim3(BP / 128, DM / 128), 256, 0, stream>>>(
        z, ObT, d_out, DM, DM, Ob, nullptr, nullptr);
}

// Round 5
// 332.341 us; speedup vs baseline: 4.0983x; 1.1494x over previous
//
#include <hip/hip_runtime.h>

#define BB 2
#define SS 2048
#define DM 1024
#define NH 16
#define DH 64
#define BP (BB*SS)            // 4096
#define BHSD (BB*NH*SS*DH)    // 4,194,304 elements

typedef __attribute__((ext_vector_type(8))) short short8v;   // 8 x bf16 (4 VGPR)
typedef __attribute__((ext_vector_type(4))) float float4v;   // MFMA C/D

// round-to-nearest-even fp32 -> bf16 (finite inputs)
__device__ __forceinline__ unsigned short f2bf(float f) {
    unsigned int u = __float_as_uint(f);
    u += 0x7fffu + ((u >> 16) & 1u);
    return (unsigned short)(u >> 16);
}

__device__ __forceinline__ short8v ld8(const unsigned short* p) {
    return *(const short8v*)p;
}

// async global->LDS, 16B per lane; LDS dest = wave-uniform base + lane*16
__device__ __forceinline__ void async_cp16(const void* g, void* l) {
    __builtin_amdgcn_global_load_lds(
        (const __attribute__((address_space(1))) unsigned int*)g,
        (__attribute__((address_space(3))) unsigned int*)l, 16, 0, 0);
}

// ---------------------------------------------------------------------------
// x (fp32 [4096][1024]) -> xb (bf16), vectorized 8/thread
// ---------------------------------------------------------------------------
__global__ __launch_bounds__(256) void k_cvtx(const float* __restrict__ x,
                                              unsigned short* __restrict__ xb) {
    const size_t i = (size_t)blockIdx.x * 256 + threadIdx.x;
    const float4 a = ((const float4*)x)[i * 2];
    const float4 b = ((const float4*)x)[i * 2 + 1];
    uint4 o;
    o.x = f2bf(a.x) | ((unsigned)f2bf(a.y) << 16);
    o.y = f2bf(a.z) | ((unsigned)f2bf(a.w) << 16);
    o.z = f2bf(b.x) | ((unsigned)f2bf(b.y) << 16);
    o.w = f2bf(b.z) | ((unsigned)f2bf(b.w) << 16);
    ((uint4*)xb)[i] = o;
}

// ---------------------------------------------------------------------------
// Weight repack: transpose+convert fp32 [1024][C] -> bf16 [C][1024].
// z<48: QKV head matrices (C=64) -> WbT rows (set*16+h)*64+dh.  z=48: O -> ObT.
// ---------------------------------------------------------------------------
__global__ __launch_bounds__(256) void k_wrepack(
    const float* __restrict__ Qs, const float* __restrict__ Ks,
    const float* __restrict__ Vs, const float* __restrict__ O,
    unsigned short* __restrict__ WbT, unsigned short* __restrict__ ObT)
{
    __shared__ float t[64][65];
    const int z = blockIdx.z;
    const float* src; unsigned short* dst; int C;
    if (z < 48) {
        if (blockIdx.y != 0) return;          // block-uniform early exit
        const int set = z >> 4, h = z & 15;
        src = ((set == 0) ? Qs : (set == 1) ? Ks : Vs) + (size_t)h * DM * DH;
        dst = WbT + (size_t)z * DH * DM;
        C = DH;
    } else { src = O; dst = ObT; C = DM; }
    const int r0 = blockIdx.x * 64, c0 = blockIdx.y * 64;
    const int tid = threadIdx.x, c = tid & 63, r4 = tid >> 6;
    #pragma unroll
    for (int i = 0; i < 16; ++i) {
        int r = r4 + i * 4;
        t[r][c] = src[(size_t)(r0 + r) * C + c0 + c];
    }
    __syncthreads();
    #pragma unroll
    for (int i = 0; i < 16; ++i) {
        int rr = r4 + i * 4;                  // source col within tile
        dst[(size_t)(c0 + rr) * DM + r0 + c] = f2bf(t[c][rr]);  // pad-65: conflict-free
    }
}

// ---------------------------------------------------------------------------
// bf16 transpose v [b][h][s][64] -> vT [b][h][64][s]
// ---------------------------------------------------------------------------
__global__ __launch_bounds__(256) void k_vt(const unsigned short* __restrict__ v,
                                            unsigned short* __restrict__ vT) {
    __shared__ unsigned short t[64][66];      // pad 66: col-read 2-way (free)
    const int bh = blockIdx.y;
    const int s0 = blockIdx.x * 64;
    const unsigned short* src = v + (size_t)bh * SS * DH + (size_t)s0 * DH;
    unsigned short* dst = vT + (size_t)bh * DH * SS + s0;
    const int tid = threadIdx.x, c = tid & 63, r4 = tid >> 6;
    #pragma unroll
    for (int i = 0; i < 16; ++i) { int r = r4 + i * 4; t[r][c] = src[r * DH + c]; }
    __syncthreads();
    #pragma unroll
    for (int i = 0; i < 16; ++i) { int dr = r4 + i * 4; dst[(size_t)dr * SS + c] = t[c][dr]; }
}

// ---------------------------------------------------------------------------
// bf16 MFMA GEMM, m97 structure: C[M][N] = A[M][K] * B[N][K]^T.
// 128x128 tile, BK=32, 4 waves (2x2), each wave 64x64 = 4x4 MFMA frags.
// MODE 0: qkv epilogue (bf16, scatter to [set][b][h][s][dh], +bias per set)
// MODE 1: fp32 row-major out, +bias
// ---------------------------------------------------------------------------
template<int MODE>
__global__ __launch_bounds__(256) void k_gemm(
    const unsigned short* __restrict__ A, const unsigned short* __restrict__ Bm,
    void* __restrict__ Cout, int N, int K,
    const float* __restrict__ bq, const float* __restrict__ bk,
    const float* __restrict__ bv)
{
    __shared__ __align__(16) unsigned short Al[128 * 32];   // [row][32k] linear, 64B rows
    __shared__ __align__(16) unsigned short Bl[128 * 32];
    const int tid = threadIdx.x;
    const int w = tid >> 6, l = tid & 63;
    const int ll = l & 15, lh = l >> 4;
    const int m0 = blockIdx.x * 128, n0 = blockIdx.y * 128;
    const int wm = w >> 1, wn = w & 1;
    const int sr = l >> 2, sc = l & 3;        // staging: lane -> (row, 16B-chunk)

    const float4v vzero = {0.f, 0.f, 0.f, 0.f};
    float4v acc[4][4];
    #pragma unroll
    for (int i = 0; i < 4; ++i)
        #pragma unroll
        for (int j = 0; j < 4; ++j) acc[i][j] = vzero;

    for (int k0 = 0; k0 < K; k0 += 32) {
        __syncthreads();                      // previous tile fully consumed
        #pragma unroll
        for (int half = 0; half < 2; ++half) {
            const int r = w * 32 + half * 16 + sr;
            async_cp16(A + (size_t)(m0 + r) * K + k0 + sc * 8,
                       &Al[(w * 32 + half * 16) * 32]);
            async_cp16(Bm + (size_t)(n0 + r) * K + k0 + sc * 8,
                       &Bl[(w * 32 + half * 16) * 32]);
        }
        __syncthreads();                      // compiler drains vmcnt before barrier

        short8v af[4], bfr[4];
        #pragma unroll
        for (int mi = 0; mi < 4; ++mi)
            af[mi] = *(const short8v*)&Al[(wm * 64 + mi * 16 + ll) * 32 + lh * 8];
        #pragma unroll
        for (int ni = 0; ni < 4; ++ni)
            bfr[ni] = *(const short8v*)&Bl[(wn * 64 + ni * 16 + ll) * 32 + lh * 8];
        #pragma unroll
        for (int mi = 0; mi < 4; ++mi)
            #pragma unroll
            for (int ni = 0; ni < 4; ++ni)
                acc[mi][ni] = __builtin_amdgcn_mfma_f32_16x16x32_bf16(
                    af[mi], bfr[ni], acc[mi][ni], 0, 0, 0);
    }

    // epilogue: C/D layout col=lane&15, row=(lane>>4)*4+reg  [m89-verified]
    #pragma unroll
    for (int mi = 0; mi < 4; ++mi)
        #pragma unroll
        for (int ni = 0; ni < 4; ++ni)
            #pragma unroll
            for (int r = 0; r < 4; ++r) {
                const int gm = m0 + wm * 64 + mi * 16 + lh * 4 + r;
                const int gn = n0 + wn * 64 + ni * 16 + ll;
                float val = acc[mi][ni][r];
                if (MODE == 0) {
                    const int set = gn >> 10, h = (gn >> 6) & 15, dh = gn & 63;
                    const float* bias = (set == 0) ? bq : (set == 1) ? bk : bv;
                    val += bias[(h << 6) + dh];
                    const int b_ = gm >> 11, s = gm & 2047;
                    ((unsigned short*)Cout)[(size_t)set * BHSD +
                        (((size_t)(b_ * NH + h) * SS + s) << 6) + dh] = f2bf(val);
                } else {
                    val += bq[gn];
                    ((float*)Cout)[(size_t)gm * N + gn] = val;
                }
            }
}

// ---------------------------------------------------------------------------
// Flash attention, bf16 MFMA, round-4 version:
//  - 1D grid, XCD-grouped: 4 bh per XCD so all q-tiles of a bh share one L2
//  - depth-1 pipeline: current-V loads + next-K prefetch issued before softmax
//  - deferred row-sum: lane-partial lrow, single shuffle-reduce at epilogue
//  - s_setprio(1) around MFMA clusters
// Wave w owns q rows qt*64 + w*16 .. +16; zero barriers.
// ---------------------------------------------------------------------------
__global__ __launch_bounds__(256, 3) void k_attn(
    const unsigned short* __restrict__ qg, const unsigned short* __restrict__ kg,
    const unsigned short* __restrict__ vtg, unsigned short* __restrict__ zg)
{
    __shared__ __align__(16) float Plds[4][16][68];
    const int tid = threadIdx.x, w = tid >> 6, l = tid & 63;
    const int ll = l & 15, lh = l >> 4;
    // XCD-aware decode: HW round-robins wgid -> XCD (wgid % 8).
    const unsigned bid = blockIdx.x;          // 0..1023
    const unsigned xcd = bid & 7, within = bid >> 3;
    const int bh = (int)((xcd << 2) | (within >> 5));   // 4 bh per XCD
    const int qt = 31 - (int)(within & 31);             // heavy q-tiles first
    const int q0 = qt * 64 + w * 16;
    const unsigned short* qb = qg + (size_t)bh * SS * DH;
    const unsigned short* kb = kg + (size_t)bh * SS * DH;
    const unsigned short* vb = vtg + (size_t)bh * DH * SS;

    short8v qf[2];      // A-frag: lane holds Q[row=ll][k=lh*8+j] (+32 for second)
    qf[0] = ld8(qb + (size_t)(q0 + ll) * DH + lh * 8);
    qf[1] = ld8(qb + (size_t)(q0 + ll) * DH + 32 + lh * 8);

    const float4v vzero = {0.f, 0.f, 0.f, 0.f};
    float4v zacc[4];
    #pragma unroll
    for (int n = 0; n < 4; ++n) zacc[n] = vzero;
    float mrow[4] = {-1e30f, -1e30f, -1e30f, -1e30f};
    float lrow[4] = {0.f, 0.f, 0.f, 0.f};     // lane-PARTIAL sums (deferred reduce)

    // preload K fragments for jt=0
    short8v kf[8];
    #pragma unroll
    for (int n = 0; n < 4; ++n) {
        kf[n * 2]     = ld8(kb + (size_t)(n * 16 + ll) * DH + lh * 8);
        kf[n * 2 + 1] = ld8(kb + (size_t)(n * 16 + ll) * DH + 32 + lh * 8);
    }

    for (int jt = 0; jt <= qt; ++jt) {
        // ---- issue current-V loads + next-K prefetch EARLY (hide under softmax)
        const unsigned short* vt = vb + jt * 64;
        short8v vf[8];
        #pragma unroll
        for (int n = 0; n < 4; ++n) {
            vf[n * 2]     = ld8(vt + (size_t)(n * 16 + ll) * SS + lh * 8);
            vf[n * 2 + 1] = ld8(vt + (size_t)(n * 16 + ll) * SS + 32 + lh * 8);
        }
        const int jn = (jt < qt) ? jt + 1 : jt;   // clamped (redundant last iter)
        const unsigned short* ktn = kb + (size_t)jn * 64 * DH;
        short8v nkf[8];
        #pragma unroll
        for (int n = 0; n < 4; ++n) {
            nkf[n * 2]     = ld8(ktn + (size_t)(n * 16 + ll) * DH + lh * 8);
            nkf[n * 2 + 1] = ld8(ktn + (size_t)(n * 16 + ll) * DH + 32 + lh * 8);
        }

        // ---- S = Q K^T / 8 ----
        float4v sv[4];
        __builtin_amdgcn_s_setprio(1);
        #pragma unroll
        for (int n = 0; n < 4; ++n) {
            float4v t = vzero;
            t = __builtin_amdgcn_mfma_f32_16x16x32_bf16(qf[0], kf[n * 2], t, 0, 0, 0);
            t = __builtin_amdgcn_mfma_f32_16x16x32_bf16(qf[1], kf[n * 2 + 1], t, 0, 0, 0);
            sv[n] = t;
        }
        __builtin_amdgcn_s_setprio(0);

        const bool diag = (jt == qt);
        #pragma unroll
        for (int n = 0; n < 4; ++n)
            #pragma unroll
            for (int r = 0; r < 4; ++r) {
                float xv = sv[n][r] * 0.125f;
                if (diag && (jt * 64 + n * 16 + ll) > (q0 + lh * 4 + r)) xv = -1e30f;
                sv[n][r] = xv;
            }

        // ---- online softmax: exact running max; lane-partial sum (no sum shfl)
        #pragma unroll
        for (int r = 0; r < 4; ++r) {
            float mx = fmaxf(fmaxf(sv[0][r], sv[1][r]), fmaxf(sv[2][r], sv[3][r]));
            #pragma unroll
            for (int o = 1; o < 16; o <<= 1) mx = fmaxf(mx, __shfl_xor(mx, o, 64));
            const float mn = fmaxf(mrow[r], mx);
            const float corr = __expf(mrow[r] - mn);
            mrow[r] = mn;
            float ps = 0.f;
            #pragma unroll
            for (int n = 0; n < 4; ++n) {
                const float p = __expf(sv[n][r] - mn);
                sv[n][r] = p; ps += p;
            }
            lrow[r] = lrow[r] * corr + ps;    // lane-partial; reduced at epilogue
            #pragma unroll
            for (int n = 0; n < 4; ++n) zacc[n][r] *= corr;
            #pragma unroll
            for (int n = 0; n < 4; ++n) Plds[w][lh * 4 + r][n * 16 + ll] = sv[n][r];
        }

        // ---- P (C-layout) -> A-frags via wave-private LDS; cvt to bf16 ----
        short8v pa[2];
        #pragma unroll
        for (int kk = 0; kk < 2; ++kk)
            #pragma unroll
            for (int j = 0; j < 8; ++j)
                pa[kk][j] = (short)f2bf(Plds[w][ll][kk * 32 + lh * 8 + j]);

        // ---- z += P @ V  (V-frags already in registers) ----
        __builtin_amdgcn_s_setprio(1);
        #pragma unroll
        for (int n = 0; n < 4; ++n) {
            zacc[n] = __builtin_amdgcn_mfma_f32_16x16x32_bf16(pa[0], vf[n * 2], zacc[n], 0, 0, 0);
            zacc[n] = __builtin_amdgcn_mfma_f32_16x16x32_bf16(pa[1], vf[n * 2 + 1], zacc[n], 0, 0, 0);
        }
        __builtin_amdgcn_s_setprio(0);

        #pragma unroll
        for (int t = 0; t < 8; ++t) kf[t] = nkf[t];
    }

    // ---- deferred sum-reduce (once per block) + epilogue ----
    float inv[4];
    #pragma unroll
    for (int r = 0; r < 4; ++r) {
        float s = lrow[r];
        #pragma unroll
        for (int o = 1; o < 16; o <<= 1) s += __shfl_xor(s, o, 64);
        inv[r] = 1.f / s;
    }
    const int b_ = bh >> 4, h = bh & 15;
    #pragma unroll
    for (int n = 0; n < 4; ++n)
        #pragma unroll
        for (int r = 0; r < 4; ++r) {
            const int s = qt * 64 + w * 16 + lh * 4 + r;
            zg[(((size_t)(b_ * SS + s)) << 10) + (h << 6) + n * 16 + ll] =
                f2bf(zacc[n][r] * inv[r]);
        }
}

// ---------------------------------------------------------------------------
extern "C" void kernel_launch(void* const* d_in, const int* in_sizes, int n_in,
                              void* d_out, int out_size, void* d_ws, size_t ws_size,
                              hipStream_t stream)
{
    const float* x   = (const float*)d_in[0];
    const float* Qs  = (const float*)d_in[1];
    const float* Qbs = (const float*)d_in[2];
    const float* Ks  = (const float*)d_in[3];
    const float* Kbs = (const float*)d_in[4];
    const float* Vs  = (const float*)d_in[5];
    const float* Vbs = (const float*)d_in[6];
    const float* O   = (const float*)d_in[7];
    const float* Ob  = (const float*)d_in[8];

    unsigned short* xb  = (unsigned short*)d_ws;          // [4096][1024]
    unsigned short* WbT = xb  + (size_t)BP * DM;          // [3072][1024]
    unsigned short* ObT = WbT + (size_t)3 * NH * DH * DM; // [1024][1024]
    unsigned short* qkv = ObT + (size_t)DM * DM;          // 3 x [b][h][s][dh]
    unsigned short* vT  = qkv + (size_t)3 * BHSD;         // [b][h][dh][s]
    unsigned short* z   = vT  + (size_t)BHSD;             // [4096][1024]

    k_cvtx<<<dim3(BP * DM / 2048), 256, 0, stream>>>(x, xb);
    k_wrepack<<<dim3(16, 16, 49), 256, 0, stream>>>(Qs, Ks, Vs, O, WbT, ObT);
    k_gemm<0><<<dim3(BP / 128, 3 * DM / 128), 256, 0, stream>>>(
        xb, WbT, qkv, 3 * DM, DM, Qbs, Kbs, Vbs);
    k_vt<<<dim3(SS / 64, BB * NH), 256, 0, stream>>>(qkv + (size_t)2 * BHSD, vT);
    k_attn<<<dim3(SS / 64 * BB * NH), 256, 0, stream>>>(qkv, qkv + BHSD, vT, z);
    k_gemm<1><<<dim3(BP / 128, DM / 128), 256, 0, stream>>>(
        z, ObT, d_out, DM, DM, Ob, nullptr, nullptr);
}